// Round 13
// baseline (605.246 us; speedup 1.0000x reference)
//
#include <hip/hip_runtime.h>

#define NN 50000
#define EE 1600000
#define DD 128
#define CC 10
#define LLAY 4
#define GG 512
#define GD (GG*DD)
#define NB 196           // ceil(NN/256) coarse buckets
#define BK_EDGES 1600    // edges per binA block (1000 blocks)
#define BUCKCAP 16000    // fixed binned region per bucket (expected 8192, >8 sigma safe)
#define NSUB 16          // src sub-tiles per node list (sorted gather window)
#define SUBW 3125        // 50000/16
#define WPAD 136         // Wl row stride in shorts (272B = 17 uint4: 2-way banks = free)

static constexpr float BN_EPS = 1e-5f;
static constexpr float INV_N = 1.0f / (float)NN;

typedef __bf16 bf16x8 __attribute__((ext_vector_type(8)));
typedef float f32x4 __attribute__((ext_vector_type(4)));

static __device__ __forceinline__ float bflo(unsigned u){ return __uint_as_float(u << 16); }
static __device__ __forceinline__ float bfhi(unsigned u){ return __uint_as_float(u & 0xffff0000u); }
static __device__ __forceinline__ unsigned short f2bf(float f){
    unsigned u = __float_as_uint(f);
    return (unsigned short)((u + 0x7fffu + ((u >> 16) & 1u)) >> 16);   // RNE
}
static __device__ __forceinline__ unsigned packbf(float a, float b){
    return (unsigned)f2bf(a) | ((unsigned)f2bf(b) << 16);
}
static __device__ __forceinline__ bf16x8 ldfrag(const unsigned short* p){
    union { uint4 u; bf16x8 b; } t; t.u = *(const uint4*)p; return t.b;
}
static __device__ __forceinline__ bf16x8 asfrag(uint4 u){
    union { uint4 u; bf16x8 b; } t; t.u = u; return t.b;
}

// ---------------- setup kernels ----------------

__global__ void zero_k(int* p, int n){
    int i = blockIdx.x * 256 + threadIdx.x;
    if (i < n) p[i] = 0;
}

// all 8 weight matrices -> bf16 W^T [j][k] in ws
__global__ void wprep_k(const float* __restrict__ W1, const float* __restrict__ W2,
                        unsigned short* __restrict__ Wtall){
    int idx = blockIdx.x * 256 + threadIdx.x;         // < 8*16384
    int mat = idx >> 14; int rr = idx & 16383;
    int k = rr >> 7; int j = rr & 127;
    const float* Wsrc = (mat < 4) ? (W1 + mat * 16384) : (W2 + (mat - 4) * 16384);
    Wtall[mat * 16384 + j * 128 + k] = f2bf(Wsrc[k * 128 + j]);
}

// graph boundaries via binary search on sorted batch
__global__ void gsearch_k(const int* __restrict__ batch, int* __restrict__ gstart){
    int g = blockIdx.x * 256 + threadIdx.x;
    if (g <= GG){
        int lo = 0, hi = NN;
        while (lo < hi){ int mid = (lo + hi) >> 1; if (batch[mid] < g) lo = mid + 1; else hi = mid; }
        gstart[g] = lo;
    }
}

// Pass A: bin edges into NB fixed-capacity bucket regions (binned[b*BUCKCAP + ...]).
// bucketCur[b] accumulates the per-bucket count (pre-zeroed).
__global__ __launch_bounds__(256) void binA_k(const int* __restrict__ srcA,
                                              const int* __restrict__ dstA,
                                              int* __restrict__ bucketCur,
                                              unsigned* __restrict__ binned){
    __shared__ int cnt[NB], bas[NB], off[NB];
    int tid = threadIdx.x;
    if (tid < NB){ cnt[tid] = 0; off[tid] = 0; }
    __syncthreads();
    int e0 = blockIdx.x * BK_EDGES;
    for (int i = tid; i < BK_EDGES; i += 256){
        int e = e0 + i;
        if (e < EE) atomicAdd(&cnt[dstA[e] >> 8], 1);
    }
    __syncthreads();
    if (tid < NB && cnt[tid] > 0) bas[tid] = atomicAdd(&bucketCur[tid], cnt[tid]);
    __syncthreads();
    for (int i = tid; i < BK_EDGES; i += 256){
        int e = e0 + i;
        if (e < EE){
            int d = dstA[e]; int b = d >> 8;
            int p = b * BUCKCAP + bas[b] + atomicAdd(&off[b], 1);
            binned[p] = (unsigned)srcA[e] | ((unsigned)(d & 255) << 17);  // src<2^17
        }
    }
}

// scan bucket counts (post-binA) -> bucketBase; terminal rp entry
__global__ __launch_bounds__(256) void bscan_k(const int* __restrict__ bucketCur,
                                               int* __restrict__ bucketBase,
                                               int* __restrict__ rp){
    __shared__ int lds[256];
    int t = threadIdx.x;
    int v = (t < NB) ? bucketCur[t] : 0;
    lds[t] = v; __syncthreads();
    for (int o = 1; o < 256; o <<= 1){
        int xv = 0; if (t >= o) xv = lds[t - o];
        __syncthreads(); lds[t] += xv; __syncthreads();
    }
    int excl = lds[t] - v;
    if (t < NB) bucketBase[t] = excl;
    if (t == 0){ bucketBase[NB] = EE; rp[NN] = EE; }
}

// Pass B (1024 thr): per-bucket (node, 16-subtile) counts -> rp + src-sorted placement.
__global__ __launch_bounds__(1024) void binB_k(const unsigned* __restrict__ binned,
                                               const int* __restrict__ bucketCur,
                                               const int* __restrict__ bucketBase,
                                               int* __restrict__ rp,
                                               int* __restrict__ ssort){
    __shared__ int c16[256 * NSUB];   // 16 KB
    __shared__ int b16[256 * NSUB];   // 16 KB
    __shared__ int nt[256];
    int b = blockIdx.x, tid = threadIdx.x;
    int nb0 = b * 256;
    int nmax = NN - nb0; if (nmax > 256) nmax = 256;
    for (int i = tid; i < 256 * NSUB; i += 1024) c16[i] = 0;
    __syncthreads();
    int cntb = bucketCur[b];
    int src0 = b * BUCKCAP;
    int base = bucketBase[b];
    for (int i = tid; i < cntb; i += 1024){
        unsigned u = binned[src0 + i];
        int src = (int)(u & 0x1FFFFu); int dl = (int)(u >> 17);
        atomicAdd(&c16[dl * NSUB + src / SUBW], 1);
    }
    __syncthreads();
    int cc[NSUB]; int tot = 0;
    if (tid < 256){
        #pragma unroll
        for (int k = 0; k < NSUB; k++){ cc[k] = c16[tid * NSUB + k]; tot += cc[k]; }
        nt[tid] = tot;
    }
    __syncthreads();
    for (int o = 1; o < 256; o <<= 1){
        int xv = 0;
        if (tid < 256 && tid >= o) xv = nt[tid - o];
        __syncthreads();
        if (tid < 256) nt[tid] += xv;
        __syncthreads();
    }
    if (tid < 256){
        int p = base + nt[tid] - tot;
        if (tid < nmax) rp[nb0 + tid] = p;
        int run = p;
        #pragma unroll
        for (int k = 0; k < NSUB; k++){ b16[tid * NSUB + k] = run; run += cc[k]; }
    }
    __syncthreads();
    for (int i = tid; i < 256 * NSUB; i += 1024) c16[i] = 0;
    __syncthreads();
    for (int i = tid; i < cntb; i += 1024){
        unsigned u = binned[src0 + i];
        int src = (int)(u & 0x1FFFFu); int dl = (int)(u >> 17);
        int t = src / SUBW;
        int pos = b16[dl * NSUB + t] + atomicAdd(&c16[dl * NSUB + t], 1);
        ssort[pos] = src;
    }
}

// x (fp32) -> bf16 h, fused with graph pooling of x. 4 blocks per graph.
__global__ __launch_bounds__(256) void convxpool_k(const float2* __restrict__ x2,
                                                   const int* __restrict__ gstart,
                                                   unsigned* __restrict__ h32,
                                                   float* __restrict__ outp){
    __shared__ float sd[512];
    int b = blockIdx.x; int gid = b >> 2, chunk = b & 3;
    int tid = threadIdx.x; int c = tid & 63, rs = tid >> 6;
    int s = gstart[gid], e = gstart[gid + 1];
    float a0 = 0.f, a1 = 0.f;
    for (int n = s + chunk * 4 + rs; n < e; n += 16){
        float2 v = x2[n * 64 + c];
        h32[n * 64 + c] = packbf(v.x, v.y);
        a0 += v.x; a1 += v.y;
    }
    sd[tid] = a0; sd[256 + tid] = a1; __syncthreads();
    if (tid < 64){
        float r0 = 0.f, r1 = 0.f;
        #pragma unroll
        for (int k2 = 0; k2 < 4; k2++){ r0 += sd[tid + 64 * k2]; r1 += sd[256 + tid + 64 * k2]; }
        atomicAdd(&outp[gid * 128 + 2 * tid], r0);
        atomicAdd(&outp[gid * 128 + 2 * tid + 1], r1);
    }
}

// ---------------- per-layer kernels ----------------

// z = h + sum_{in-edges} h[src]  (dword gathers, unroll 16)
__global__ __launch_bounds__(256) void agg_k(const unsigned* __restrict__ h32,
                                             const int* __restrict__ rp,
                                             const int* __restrict__ ssort,
                                             unsigned* __restrict__ z32,
                                             float* __restrict__ zstats){
    int tid = threadIdx.x;
    if (blockIdx.x == 0) zstats[tid] = 0.f;
    int n = blockIdx.x * 4 + (tid >> 6);  // grid*4 == NN exactly
    int lane = tid & 63;
    unsigned self = h32[n * 64 + lane];
    float ax = bflo(self), ay = bfhi(self);
    int e  = __builtin_amdgcn_readfirstlane(rp[n]);
    int e1 = __builtin_amdgcn_readfirstlane(rp[n + 1]);
    for (; e + 15 < e1; e += 16){
        int sA[16];
        #pragma unroll
        for (int k = 0; k < 16; k++) sA[k] = ssort[e + k];
        unsigned uA[16];
        #pragma unroll
        for (int k = 0; k < 16; k++) uA[k] = h32[sA[k] * 64 + lane];
        #pragma unroll
        for (int k = 0; k < 16; k++){ ax += bflo(uA[k]); ay += bfhi(uA[k]); }
    }
    for (; e + 3 < e1; e += 4){
        int s0 = ssort[e], s1 = ssort[e + 1], s2 = ssort[e + 2], s3 = ssort[e + 3];
        unsigned u0 = h32[s0 * 64 + lane];
        unsigned u1 = h32[s1 * 64 + lane];
        unsigned u2 = h32[s2 * 64 + lane];
        unsigned u3 = h32[s3 * 64 + lane];
        ax += bflo(u0) + bflo(u1); ay += bfhi(u0) + bfhi(u1);
        ax += bflo(u2) + bflo(u3); ay += bfhi(u2) + bfhi(u3);
    }
    for (; e < e1; ++e){
        unsigned u0 = h32[ssort[e] * 64 + lane];
        ax += bflo(u0); ay += bfhi(u0);
    }
    z32[n * 64 + lane] = packbf(ax, ay);
}

// C[64-row tile, 64-col slice] = opt_relu_bn(A) @ W-slice + bias, bf16 MFMA 16x16x32.
// blockIdx = tile*2 + slice; 1564 blocks (6/CU). A-frags direct from global; Wl padded.
// Fused epilogue: column sum/sumsq -> atomicAdd into ostats. Blocks 0..255 zero zpool if given.
template<int TR>
__global__ __launch_bounds__(256) void gemm_k(const unsigned* __restrict__ A32,
                                              const unsigned short* __restrict__ Wtg,
                                              const float* __restrict__ bias,
                                              unsigned short* __restrict__ Cst,
                                              const float* __restrict__ stats,
                                              const float* __restrict__ gma,
                                              const float* __restrict__ bta,
                                              float* __restrict__ ostats,
                                              float* __restrict__ zstats,
                                              float* __restrict__ zpool){
    __shared__ __align__(16) unsigned short Wl[64 * WPAD];  // 17.4KB, [j][k] padded
    __shared__ float sred[512];
    __shared__ __align__(16) float sl[128], tl[128];
    int tid = threadIdx.x;
    int slice = blockIdx.x & 1;
    int tileb = blockIdx.x >> 1;
    if (blockIdx.x == 0 && zstats) zstats[tid] = 0.f;
    if (zpool && blockIdx.x < 256) zpool[blockIdx.x * 256 + tid] = 0.f;
    {   // stage 64 W^T rows [slice*64, slice*64+64): each row = 16 uint4, padded to 17
        const uint4* src = (const uint4*)(Wtg + slice * 64 * 128);
        uint4* dst = (uint4*)Wl;
        #pragma unroll
        for (int i = 0; i < 4; i++){
            int idx = tid + 256 * i;            // 0..1023
            int row = idx >> 4, c16 = idx & 15; // 64 rows x 16 uint4
            dst[row * (WPAD / 8) + c16] = src[idx];
        }
    }
    if (TR && tid < 128){
        float mean = stats[tid] * INV_N;
        float q    = stats[128 + tid] * INV_N;
        float inv  = rsqrtf(q - mean * mean + BN_EPS);
        float s    = gma[tid] * inv;
        sl[tid] = s; tl[tid] = bta[tid] - mean * s;
    }
    __syncthreads();

    int wv = tid >> 6, lane = tid & 63;
    int rowbase = tileb * 64 + wv * 16;
    int r0 = rowbase + (lane & 15);
    int kd = (lane >> 4) * 4;       // dword offset within 16-dword k-group

    uint4 va[4];
    #pragma unroll
    for (int ks = 0; ks < 4; ks++)
        va[ks] = (r0 < NN) ? *(const uint4*)(A32 + r0 * 64 + ks * 16 + kd) : make_uint4(0,0,0,0);
    if (TR){
        #pragma unroll
        for (int ks = 0; ks < 4; ks++){
            int q = ks * 8 + (lane >> 4) * 2;       // float4 index: k0/4
            float4 sA = ((const float4*)sl)[q], sB = ((const float4*)sl)[q + 1];
            float4 tA = ((const float4*)tl)[q], tB = ((const float4*)tl)[q + 1];
            float fs[8] = {sA.x, sA.y, sA.z, sA.w, sB.x, sB.y, sB.z, sB.w};
            float ft[8] = {tA.x, tA.y, tA.z, tA.w, tB.x, tB.y, tB.z, tB.w};
            unsigned* pa = (unsigned*)&va[ks];
            #pragma unroll
            for (int c = 0; c < 4; c++){
                float f0 = fmaxf(bflo(pa[c]) * fs[2*c] + ft[2*c], 0.f);
                float f1 = fmaxf(bfhi(pa[c]) * fs[2*c+1] + ft[2*c+1], 0.f);
                pa[c] = packbf(f0, f1);
            }
        }
    }

    f32x4 acc[4];
    #pragma unroll
    for (int b = 0; b < 4; b++) acc[b] = (f32x4){0.f, 0.f, 0.f, 0.f};

    #pragma unroll
    for (int ks = 0; ks < 4; ks++){
        int wk = ks * 32 + (lane >> 4) * 8;
        bf16x8 a0 = asfrag(va[ks]);
        #pragma unroll
        for (int ct = 0; ct < 4; ++ct){
            bf16x8 b = ldfrag(&Wl[(ct * 16 + (lane & 15)) * WPAD + wk]);
            acc[ct] = __builtin_amdgcn_mfma_f32_16x16x32_bf16(a0, b, acc[ct], 0, 0, 0);
        }
    }

    // epilogue: C/D layout col=lane&15, row=(lane>>4)*4+reg. Store + column stats.
    int cl = lane & 15, rq = lane >> 4;
    float colS[4], colQ[4];
    #pragma unroll
    for (int ct = 0; ct < 4; ++ct){
        int col = slice * 64 + ct * 16 + cl;
        float bv = bias[col];
        float ps = 0.f, pq = 0.f;
        #pragma unroll
        for (int rr2 = 0; rr2 < 4; ++rr2){
            int grow = rowbase + rq * 4 + rr2;
            if (grow < NN){
                float val = acc[ct][rr2] + bv;
                Cst[grow * 128 + col] = f2bf(val);
                ps += val; pq += val * val;
            }
        }
        ps += __shfl_xor(ps, 16); pq += __shfl_xor(pq, 16);
        ps += __shfl_xor(ps, 32); pq += __shfl_xor(pq, 32);
        colS[ct] = ps; colQ[ct] = pq;
    }
    if (rq == 0){
        #pragma unroll
        for (int ct = 0; ct < 4; ++ct){
            sred[wv * 64 + ct * 16 + cl]       = colS[ct];
            sred[256 + wv * 64 + ct * 16 + cl] = colQ[ct];
        }
    }
    __syncthreads();
    if (tid < 64){
        float s1 = sred[tid] + sred[64 + tid] + sred[128 + tid] + sred[192 + tid];
        float s2 = sred[256 + tid] + sred[320 + tid] + sred[384 + tid] + sred[448 + tid];
        atomicAdd(&ostats[slice * 64 + tid], s1);
        atomicAdd(&ostats[128 + slice * 64 + tid], s2);
    }
}

// h = relu(bn(z)) (write h) fused with per-graph pooling. 4 blocks per graph.
__global__ __launch_bounds__(256) void ewpool_k(const unsigned* __restrict__ z32,
                                                const float* __restrict__ stats,
                                                const float* __restrict__ g,
                                                const float* __restrict__ b,
                                                const int* __restrict__ gstart,
                                                unsigned* __restrict__ h32,
                                                float* __restrict__ outp){
    __shared__ float sd[512];
    int blk = blockIdx.x; int gid = blk >> 2, chunk = blk & 3;
    int tid = threadIdx.x;
    int c = tid & 63, rs = tid >> 6;
    int c2 = c * 2;
    float m0 = stats[c2] * INV_N,     q0 = stats[128 + c2] * INV_N;
    float inv0 = rsqrtf(q0 - m0 * m0 + BN_EPS);
    float s0 = g[c2] * inv0, t0 = b[c2] - m0 * s0;
    float m1 = stats[c2 + 1] * INV_N, q1 = stats[129 + c2] * INV_N;
    float inv1 = rsqrtf(q1 - m1 * m1 + BN_EPS);
    float s1 = g[c2 + 1] * inv1, t1 = b[c2 + 1] - m1 * s1;
    int s = gstart[gid], e = gstart[gid + 1];
    float a0 = 0.f, a1 = 0.f;
    int n = s + chunk * 4 + rs;
    for (; n + 16 < e; n += 32){
        unsigned u0 = z32[n * 64 + c];
        unsigned u1 = z32[(n + 16) * 64 + c];
        float f0, f1;
        f0 = fmaxf(bflo(u0) * s0 + t0, 0.f); f1 = fmaxf(bfhi(u0) * s1 + t1, 0.f);
        h32[n * 64 + c] = packbf(f0, f1); a0 += f0; a1 += f1;
        f0 = fmaxf(bflo(u1) * s0 + t0, 0.f); f1 = fmaxf(bfhi(u1) * s1 + t1, 0.f);
        h32[(n + 16) * 64 + c] = packbf(f0, f1); a0 += f0; a1 += f1;
    }
    for (; n < e; n += 16){
        unsigned u = z32[n * 64 + c];
        float f0 = fmaxf(bflo(u) * s0 + t0, 0.f);
        float f1 = fmaxf(bfhi(u) * s1 + t1, 0.f);
        h32[n * 64 + c] = packbf(f0, f1);
        a0 += f0; a1 += f1;
    }
    sd[tid] = a0; sd[256 + tid] = a1; __syncthreads();
    if (tid < 64){
        float r0 = 0.f, r1 = 0.f;
        #pragma unroll
        for (int k2 = 0; k2 < 4; k2++){ r0 += sd[tid + 64 * k2]; r1 += sd[256 + tid + 64 * k2]; }
        atomicAdd(&outp[gid * 128 + 2 * tid], r0);
        atomicAdd(&outp[gid * 128 + 2 * tid + 1], r1);
    }
}

// logits = sum_i pooled_i @ fcW_i + fcb_i ; out = log_softmax(logits)
__global__ __launch_bounds__(64) void final_k(const float* __restrict__ pooled,
                                              const float* __restrict__ fcW,
                                              const float* __restrict__ fcb,
                                              float* __restrict__ out){
    int g = blockIdx.x, l = threadIdx.x;
    float p0[5], p1[5];
    #pragma unroll
    for (int i = 0; i < 5; i++){
        p0[i] = pooled[i * GD + g * 128 + l];
        p1[i] = pooled[i * GD + g * 128 + 64 + l];
    }
    float lg[10];
    #pragma unroll
    for (int c2 = 0; c2 < 10; c2++){
        float s = 0;
        #pragma unroll
        for (int i = 0; i < 5; i++){
            s += p0[i] * fcW[(i * 128 + l) * 10 + c2];
            s += p1[i] * fcW[(i * 128 + 64 + l) * 10 + c2];
        }
        #pragma unroll
        for (int off = 32; off >= 1; off >>= 1) s += __shfl_down(s, off);
        lg[c2] = s;
    }
    if (l == 0){
        #pragma unroll
        for (int c2 = 0; c2 < 10; c2++){
            float bs = 0;
            #pragma unroll
            for (int i = 0; i < 5; i++) bs += fcb[i * 10 + c2];
            lg[c2] += bs;
        }
        float mx = lg[0];
        #pragma unroll
        for (int c2 = 1; c2 < 10; c2++) mx = fmaxf(mx, lg[c2]);
        float se = 0;
        #pragma unroll
        for (int c2 = 0; c2 < 10; c2++) se += expf(lg[c2] - mx);
        float lse = mx + logf(se);
        #pragma unroll
        for (int c2 = 0; c2 < 10; c2++) out[g * 10 + c2] = lg[c2] - lse;
    }
}

// ---------------- launch ----------------

extern "C" void kernel_launch(void* const* d_in, const int* in_sizes, int n_in,
                              void* d_out, int out_size, void* d_ws, size_t ws_size,
                              hipStream_t stream){
    (void)in_sizes; (void)n_in; (void)out_size; (void)ws_size;
    const float* x     = (const float*)d_in[0];
    const int*   ei    = (const int*)d_in[1];
    const int*   batch = (const int*)d_in[2];
    const float* cW1   = (const float*)d_in[4];
    const float* cb1   = (const float*)d_in[5];
    const float* cbng  = (const float*)d_in[6];
    const float* cbnb  = (const float*)d_in[7];
    const float* cW2   = (const float*)d_in[8];
    const float* cb2   = (const float*)d_in[9];
    const float* bng   = (const float*)d_in[10];
    const float* bnb   = (const float*)d_in[11];
    const float* fcW   = (const float*)d_in[12];
    const float* fcb   = (const float*)d_in[13];

    char* base = (char*)d_ws;
    size_t off = 0;
    auto alloc = [&](size_t bytes) -> void* {
        void* p = base + off;
        off = (off + bytes + 255) & ~(size_t)255;
        return p;
    };
    unsigned*       hB     = (unsigned*)alloc((size_t)NN * 64 * 4);
    unsigned*       zA     = (unsigned*)alloc((size_t)NN * 64 * 4);
    unsigned*       zB     = (unsigned*)alloc((size_t)NN * 64 * 4);   // also binned (NB*BUCKCAP*4 = 12.54MB)
    unsigned short* Wtall  = (unsigned short*)alloc(8 * 16384 * 2);
    int*            ssort  = (int*)alloc((size_t)EE * 4);
    int*            rp     = (int*)alloc((NN + 1) * 4);
    int*            gstart = (int*)alloc((GG + 1) * 4);
    int*            bucketBase = (int*)alloc((NB + 1) * 4);
    // ---- contiguous zero region: bucketCur .. pooled slot 0 ----
    int*            bucketCur  = (int*)alloc(NB * 4);
    float*          pooled = (float*)alloc((size_t)5 * GD * 4);
    // ------------------------------------------------------------
    float*          stats1 = (float*)alloc(256 * 4);
    float*          stats2 = (float*)alloc(256 * 4);
    unsigned*       binned = (unsigned*)zB;   // alias: binned only used before layer loop

    int zwords = (int)(((char*)(pooled + GD) - (char*)bucketCur) / 4);  // incl. pooled[0] slot

    zero_k<<<(zwords + 255) / 256, 256, 0, stream>>>(bucketCur, zwords);
    wprep_k<<<512, 256, 0, stream>>>(cW1, cW2, Wtall);
    gsearch_k<<<3, 256, 0, stream>>>(batch, gstart);
    binA_k<<<(EE + BK_EDGES - 1) / BK_EDGES, 256, 0, stream>>>(ei, ei + EE, bucketCur, binned);
    bscan_k<<<1, 256, 0, stream>>>(bucketCur, bucketBase, rp);
    binB_k<<<NB, 1024, 0, stream>>>(binned, bucketCur, bucketBase, rp, ssort);
    convxpool_k<<<4 * GG, 256, 0, stream>>>((const float2*)x, gstart, hB, pooled);

    const int gemmGrid = 2 * ((NN + 63) / 64);
    for (int i = 0; i < LLAY; i++){
        agg_k<<<NN / 4, 256, 0, stream>>>(hB, rp, ssort, zA, stats1);
        gemm_k<0><<<gemmGrid, 256, 0, stream>>>(zA, Wtall + i * 16384, cb1 + i * 128,
                                                (unsigned short*)zB,
                                                nullptr, nullptr, nullptr, stats1, stats2, nullptr);
        gemm_k<1><<<gemmGrid, 256, 0, stream>>>(zB, Wtall + (4 + i) * 16384, cb2 + i * 128,
                                                (unsigned short*)zA,
                                                stats1, cbng + i * 128, cbnb + i * 128, stats2, nullptr,
                                                pooled + (size_t)(i + 1) * GD);
        ewpool_k<<<4 * GG, 256, 0, stream>>>(zA, stats2, bng + i * 128, bnb + i * 128,
                                             gstart, hB, pooled + (size_t)(i + 1) * GD);
    }
    final_k<<<GG, 64, 0, stream>>>(pooled, fcW, fcb, (float*)d_out);
}

// Round 14
// 546.652 us; speedup vs baseline: 1.1072x; 1.1072x over previous
//
#include <hip/hip_runtime.h>

#define NN 50000
#define EE 1600000
#define DD 128
#define CC 10
#define LLAY 4
#define GG 512
#define GD (GG*DD)
#define NB 196           // ceil(NN/256) coarse buckets
#define BK_EDGES 1600    // edges per binA block (1000 blocks)
#define BUCKCAP 16000    // fixed binned region per bucket (expected 8192, >8 sigma safe)
#define NSUB 16          // src sub-tiles per node list (sorted gather window)
#define SUBW 3125        // 50000/16
#define WPAD 136         // Wl row stride in shorts (272B = 17 uint4: 2-way banks = free)

static constexpr float BN_EPS = 1e-5f;
static constexpr float INV_N = 1.0f / (float)NN;

typedef __bf16 bf16x8 __attribute__((ext_vector_type(8)));
typedef float f32x4 __attribute__((ext_vector_type(4)));

static __device__ __forceinline__ float bflo(unsigned u){ return __uint_as_float(u << 16); }
static __device__ __forceinline__ float bfhi(unsigned u){ return __uint_as_float(u & 0xffff0000u); }
static __device__ __forceinline__ unsigned short f2bf(float f){
    unsigned u = __float_as_uint(f);
    return (unsigned short)((u + 0x7fffu + ((u >> 16) & 1u)) >> 16);   // RNE
}
static __device__ __forceinline__ unsigned packbf(float a, float b){
    return (unsigned)f2bf(a) | ((unsigned)f2bf(b) << 16);
}
static __device__ __forceinline__ bf16x8 ldfrag(const unsigned short* p){
    union { uint4 u; bf16x8 b; } t; t.u = *(const uint4*)p; return t.b;
}
static __device__ __forceinline__ bf16x8 asfrag(uint4 u){
    union { uint4 u; bf16x8 b; } t; t.u = u; return t.b;
}

// ---------------- setup kernels ----------------

__global__ void zero_k(int* p, int n){
    int i = blockIdx.x * 256 + threadIdx.x;
    if (i < n) p[i] = 0;
}

// all 8 weight matrices -> bf16 W^T [j][k] in ws
__global__ void wprep_k(const float* __restrict__ W1, const float* __restrict__ W2,
                        unsigned short* __restrict__ Wtall){
    int idx = blockIdx.x * 256 + threadIdx.x;         // < 8*16384
    int mat = idx >> 14; int rr = idx & 16383;
    int k = rr >> 7; int j = rr & 127;
    const float* Wsrc = (mat < 4) ? (W1 + mat * 16384) : (W2 + (mat - 4) * 16384);
    Wtall[mat * 16384 + j * 128 + k] = f2bf(Wsrc[k * 128 + j]);
}

// graph boundaries via binary search on sorted batch
__global__ void gsearch_k(const int* __restrict__ batch, int* __restrict__ gstart){
    int g = blockIdx.x * 256 + threadIdx.x;
    if (g <= GG){
        int lo = 0, hi = NN;
        while (lo < hi){ int mid = (lo + hi) >> 1; if (batch[mid] < g) lo = mid + 1; else hi = mid; }
        gstart[g] = lo;
    }
}

// Pass A: bin edges into NB fixed-capacity bucket regions (binned[b*BUCKCAP + ...]).
// bucketCur[b] accumulates the per-bucket count (pre-zeroed).
__global__ __launch_bounds__(256) void binA_k(const int* __restrict__ srcA,
                                              const int* __restrict__ dstA,
                                              int* __restrict__ bucketCur,
                                              unsigned* __restrict__ binned){
    __shared__ int cnt[NB], bas[NB], off[NB];
    int tid = threadIdx.x;
    if (tid < NB){ cnt[tid] = 0; off[tid] = 0; }
    __syncthreads();
    int e0 = blockIdx.x * BK_EDGES;
    for (int i = tid; i < BK_EDGES; i += 256){
        int e = e0 + i;
        if (e < EE) atomicAdd(&cnt[dstA[e] >> 8], 1);
    }
    __syncthreads();
    if (tid < NB && cnt[tid] > 0) bas[tid] = atomicAdd(&bucketCur[tid], cnt[tid]);
    __syncthreads();
    for (int i = tid; i < BK_EDGES; i += 256){
        int e = e0 + i;
        if (e < EE){
            int d = dstA[e]; int b = d >> 8;
            int p = b * BUCKCAP + bas[b] + atomicAdd(&off[b], 1);
            binned[p] = (unsigned)srcA[e] | ((unsigned)(d & 255) << 17);  // src<2^17
        }
    }
}

// scan bucket counts (post-binA) -> bucketBase; terminal rp entry
__global__ __launch_bounds__(256) void bscan_k(const int* __restrict__ bucketCur,
                                               int* __restrict__ bucketBase,
                                               int* __restrict__ rp){
    __shared__ int lds[256];
    int t = threadIdx.x;
    int v = (t < NB) ? bucketCur[t] : 0;
    lds[t] = v; __syncthreads();
    for (int o = 1; o < 256; o <<= 1){
        int xv = 0; if (t >= o) xv = lds[t - o];
        __syncthreads(); lds[t] += xv; __syncthreads();
    }
    int excl = lds[t] - v;
    if (t < NB) bucketBase[t] = excl;
    if (t == 0){ bucketBase[NB] = EE; rp[NN] = EE; }
}

// Pass B (1024 thr): per-bucket (node, 16-subtile) counts -> rp + src-sorted placement.
__global__ __launch_bounds__(1024) void binB_k(const unsigned* __restrict__ binned,
                                               const int* __restrict__ bucketCur,
                                               const int* __restrict__ bucketBase,
                                               int* __restrict__ rp,
                                               int* __restrict__ ssort){
    __shared__ int c16[256 * NSUB];   // 16 KB
    __shared__ int b16[256 * NSUB];   // 16 KB
    __shared__ int nt[256];
    int b = blockIdx.x, tid = threadIdx.x;
    int nb0 = b * 256;
    int nmax = NN - nb0; if (nmax > 256) nmax = 256;
    for (int i = tid; i < 256 * NSUB; i += 1024) c16[i] = 0;
    __syncthreads();
    int cntb = bucketCur[b];
    int src0 = b * BUCKCAP;
    int base = bucketBase[b];
    for (int i = tid; i < cntb; i += 1024){
        unsigned u = binned[src0 + i];
        int src = (int)(u & 0x1FFFFu); int dl = (int)(u >> 17);
        atomicAdd(&c16[dl * NSUB + src / SUBW], 1);
    }
    __syncthreads();
    int cc[NSUB]; int tot = 0;
    if (tid < 256){
        #pragma unroll
        for (int k = 0; k < NSUB; k++){ cc[k] = c16[tid * NSUB + k]; tot += cc[k]; }
        nt[tid] = tot;
    }
    __syncthreads();
    for (int o = 1; o < 256; o <<= 1){
        int xv = 0;
        if (tid < 256 && tid >= o) xv = nt[tid - o];
        __syncthreads();
        if (tid < 256) nt[tid] += xv;
        __syncthreads();
    }
    if (tid < 256){
        int p = base + nt[tid] - tot;
        if (tid < nmax) rp[nb0 + tid] = p;
        int run = p;
        #pragma unroll
        for (int k = 0; k < NSUB; k++){ b16[tid * NSUB + k] = run; run += cc[k]; }
    }
    __syncthreads();
    for (int i = tid; i < 256 * NSUB; i += 1024) c16[i] = 0;
    __syncthreads();
    for (int i = tid; i < cntb; i += 1024){
        unsigned u = binned[src0 + i];
        int src = (int)(u & 0x1FFFFu); int dl = (int)(u >> 17);
        int t = src / SUBW;
        int pos = b16[dl * NSUB + t] + atomicAdd(&c16[dl * NSUB + t], 1);
        ssort[pos] = src;
    }
}

// x (fp32) -> bf16 h, fused with graph pooling of x. 4 blocks per graph.
__global__ __launch_bounds__(256) void convxpool_k(const float2* __restrict__ x2,
                                                   const int* __restrict__ gstart,
                                                   unsigned* __restrict__ h32,
                                                   float* __restrict__ outp){
    __shared__ float sd[512];
    int b = blockIdx.x; int gid = b >> 2, chunk = b & 3;
    int tid = threadIdx.x; int c = tid & 63, rs = tid >> 6;
    int s = gstart[gid], e = gstart[gid + 1];
    float a0 = 0.f, a1 = 0.f;
    for (int n = s + chunk * 4 + rs; n < e; n += 16){
        float2 v = x2[n * 64 + c];
        h32[n * 64 + c] = packbf(v.x, v.y);
        a0 += v.x; a1 += v.y;
    }
    sd[tid] = a0; sd[256 + tid] = a1; __syncthreads();
    if (tid < 64){
        float r0 = 0.f, r1 = 0.f;
        #pragma unroll
        for (int k2 = 0; k2 < 4; k2++){ r0 += sd[tid + 64 * k2]; r1 += sd[256 + tid + 64 * k2]; }
        atomicAdd(&outp[gid * 128 + 2 * tid], r0);
        atomicAdd(&outp[gid * 128 + 2 * tid + 1], r1);
    }
}

// ---------------- per-layer kernels ----------------

// z = h + sum_{in-edges} h[src]  (dword gathers, unroll 16)
__global__ __launch_bounds__(256) void agg_k(const unsigned* __restrict__ h32,
                                             const int* __restrict__ rp,
                                             const int* __restrict__ ssort,
                                             unsigned* __restrict__ z32,
                                             float* __restrict__ zstats){
    int tid = threadIdx.x;
    if (blockIdx.x == 0) zstats[tid] = 0.f;
    int n = blockIdx.x * 4 + (tid >> 6);  // grid*4 == NN exactly
    int lane = tid & 63;
    unsigned self = h32[n * 64 + lane];
    float ax = bflo(self), ay = bfhi(self);
    int e  = __builtin_amdgcn_readfirstlane(rp[n]);
    int e1 = __builtin_amdgcn_readfirstlane(rp[n + 1]);
    for (; e + 15 < e1; e += 16){
        int sA[16];
        #pragma unroll
        for (int k = 0; k < 16; k++) sA[k] = ssort[e + k];
        unsigned uA[16];
        #pragma unroll
        for (int k = 0; k < 16; k++) uA[k] = h32[sA[k] * 64 + lane];
        #pragma unroll
        for (int k = 0; k < 16; k++){ ax += bflo(uA[k]); ay += bfhi(uA[k]); }
    }
    for (; e + 3 < e1; e += 4){
        int s0 = ssort[e], s1 = ssort[e + 1], s2 = ssort[e + 2], s3 = ssort[e + 3];
        unsigned u0 = h32[s0 * 64 + lane];
        unsigned u1 = h32[s1 * 64 + lane];
        unsigned u2 = h32[s2 * 64 + lane];
        unsigned u3 = h32[s3 * 64 + lane];
        ax += bflo(u0) + bflo(u1); ay += bfhi(u0) + bfhi(u1);
        ax += bflo(u2) + bflo(u3); ay += bfhi(u2) + bfhi(u3);
    }
    for (; e < e1; ++e){
        unsigned u0 = h32[ssort[e] * 64 + lane];
        ax += bflo(u0); ay += bfhi(u0);
    }
    z32[n * 64 + lane] = packbf(ax, ay);
}

// C[N, 64-col slice] = opt_relu_bn(A[N,128]) @ W-slice + bias, bf16 MFMA 16x16x32.
// R12 form: 128-row x 64-col tile, blockIdx = tile*2 + slice, 782 blocks.
// A-frags direct from global; Wl padded (WPAD) -> no bank conflicts.
// Fused epilogue: column sum/sumsq -> atomicAdd into ostats. Blocks 0..255 zero zpool if given.
template<int TR>
__global__ __launch_bounds__(256) void gemm_k(const unsigned* __restrict__ A32,
                                              const unsigned short* __restrict__ Wtg,
                                              const float* __restrict__ bias,
                                              unsigned short* __restrict__ Cst,
                                              const float* __restrict__ stats,
                                              const float* __restrict__ gma,
                                              const float* __restrict__ bta,
                                              float* __restrict__ ostats,
                                              float* __restrict__ zstats,
                                              float* __restrict__ zpool){
    __shared__ __align__(16) unsigned short Wl[64 * WPAD];  // 17.4KB, [j][k] padded
    __shared__ float sred[512];
    __shared__ __align__(16) float sl[128], tl[128];
    int tid = threadIdx.x;
    int slice = blockIdx.x & 1;
    int tileb = blockIdx.x >> 1;
    if (blockIdx.x == 0 && zstats) zstats[tid] = 0.f;
    if (zpool && blockIdx.x < 256) zpool[blockIdx.x * 256 + tid] = 0.f;
    {   // stage 64 W^T rows [slice*64, slice*64+64): each row = 16 uint4, padded to 17
        const uint4* src = (const uint4*)(Wtg + slice * 64 * 128);
        uint4* dst = (uint4*)Wl;
        #pragma unroll
        for (int i = 0; i < 4; i++){
            int idx = tid + 256 * i;            // 0..1023
            int row = idx >> 4, c16 = idx & 15; // 64 rows x 16 uint4
            dst[row * (WPAD / 8) + c16] = src[idx];
        }
    }
    if (TR && tid < 128){
        float mean = stats[tid] * INV_N;
        float q    = stats[128 + tid] * INV_N;
        float inv  = rsqrtf(q - mean * mean + BN_EPS);
        float s    = gma[tid] * inv;
        sl[tid] = s; tl[tid] = bta[tid] - mean * s;
    }
    __syncthreads();

    int wv = tid >> 6, lane = tid & 63;
    int rowbase = tileb * 128 + wv * 32;
    int r0 = rowbase + (lane & 15);
    int r1 = r0 + 16;
    int kd = (lane >> 4) * 4;       // dword offset within 16-dword k-group

    uint4 va[4], vb[4];
    #pragma unroll
    for (int ks = 0; ks < 4; ks++){
        va[ks] = (r0 < NN) ? *(const uint4*)(A32 + r0 * 64 + ks * 16 + kd) : make_uint4(0,0,0,0);
        vb[ks] = (r1 < NN) ? *(const uint4*)(A32 + r1 * 64 + ks * 16 + kd) : make_uint4(0,0,0,0);
    }
    if (TR){
        #pragma unroll
        for (int ks = 0; ks < 4; ks++){
            int q = ks * 8 + (lane >> 4) * 2;       // float4 index: k0/4
            float4 sA = ((const float4*)sl)[q], sB = ((const float4*)sl)[q + 1];
            float4 tA = ((const float4*)tl)[q], tB = ((const float4*)tl)[q + 1];
            float fs[8] = {sA.x, sA.y, sA.z, sA.w, sB.x, sB.y, sB.z, sB.w};
            float ft[8] = {tA.x, tA.y, tA.z, tA.w, tB.x, tB.y, tB.z, tB.w};
            unsigned* pa = (unsigned*)&va[ks];
            unsigned* pb = (unsigned*)&vb[ks];
            #pragma unroll
            for (int c = 0; c < 4; c++){
                float f0 = fmaxf(bflo(pa[c]) * fs[2*c] + ft[2*c], 0.f);
                float f1 = fmaxf(bfhi(pa[c]) * fs[2*c+1] + ft[2*c+1], 0.f);
                pa[c] = packbf(f0, f1);
                f0 = fmaxf(bflo(pb[c]) * fs[2*c] + ft[2*c], 0.f);
                f1 = fmaxf(bfhi(pb[c]) * fs[2*c+1] + ft[2*c+1], 0.f);
                pb[c] = packbf(f0, f1);
            }
        }
    }

    f32x4 acc[2][4];
    #pragma unroll
    for (int a = 0; a < 2; a++)
        #pragma unroll
        for (int b = 0; b < 4; b++) acc[a][b] = (f32x4){0.f, 0.f, 0.f, 0.f};

    #pragma unroll
    for (int ks = 0; ks < 4; ks++){
        int wk = ks * 32 + (lane >> 4) * 8;
        bf16x8 a0 = asfrag(va[ks]);
        bf16x8 a1 = asfrag(vb[ks]);
        #pragma unroll
        for (int ct = 0; ct < 4; ++ct){
            bf16x8 b = ldfrag(&Wl[(ct * 16 + (lane & 15)) * WPAD + wk]);
            acc[0][ct] = __builtin_amdgcn_mfma_f32_16x16x32_bf16(a0, b, acc[0][ct], 0, 0, 0);
            acc[1][ct] = __builtin_amdgcn_mfma_f32_16x16x32_bf16(a1, b, acc[1][ct], 0, 0, 0);
        }
    }

    // epilogue: C/D layout col=lane&15, row=(lane>>4)*4+reg. Store + column stats.
    int cl = lane & 15, rq = lane >> 4;
    float colS[4], colQ[4];
    #pragma unroll
    for (int ct = 0; ct < 4; ++ct){
        int col = slice * 64 + ct * 16 + cl;
        float bv = bias[col];
        float ps = 0.f, pq = 0.f;
        #pragma unroll
        for (int rt = 0; rt < 2; ++rt){
            #pragma unroll
            for (int rr2 = 0; rr2 < 4; ++rr2){
                int grow = rowbase + rt * 16 + rq * 4 + rr2;
                if (grow < NN){
                    float val = acc[rt][ct][rr2] + bv;
                    Cst[grow * 128 + col] = f2bf(val);
                    ps += val; pq += val * val;
                }
            }
        }
        ps += __shfl_xor(ps, 16); pq += __shfl_xor(pq, 16);
        ps += __shfl_xor(ps, 32); pq += __shfl_xor(pq, 32);
        colS[ct] = ps; colQ[ct] = pq;
    }
    if (rq == 0){
        #pragma unroll
        for (int ct = 0; ct < 4; ++ct){
            sred[wv * 64 + ct * 16 + cl]       = colS[ct];
            sred[256 + wv * 64 + ct * 16 + cl] = colQ[ct];
        }
    }
    __syncthreads();
    if (tid < 64){
        float s1 = sred[tid] + sred[64 + tid] + sred[128 + tid] + sred[192 + tid];
        float s2 = sred[256 + tid] + sred[320 + tid] + sred[384 + tid] + sred[448 + tid];
        atomicAdd(&ostats[slice * 64 + tid], s1);
        atomicAdd(&ostats[128 + slice * 64 + tid], s2);
    }
}

// h = relu(bn(z)) (write h) fused with per-graph pooling. 4 blocks per graph.
__global__ __launch_bounds__(256) void ewpool_k(const unsigned* __restrict__ z32,
                                                const float* __restrict__ stats,
                                                const float* __restrict__ g,
                                                const float* __restrict__ b,
                                                const int* __restrict__ gstart,
                                                unsigned* __restrict__ h32,
                                                float* __restrict__ outp){
    __shared__ float sd[512];
    int blk = blockIdx.x; int gid = blk >> 2, chunk = blk & 3;
    int tid = threadIdx.x;
    int c = tid & 63, rs = tid >> 6;
    int c2 = c * 2;
    float m0 = stats[c2] * INV_N,     q0 = stats[128 + c2] * INV_N;
    float inv0 = rsqrtf(q0 - m0 * m0 + BN_EPS);
    float s0 = g[c2] * inv0, t0 = b[c2] - m0 * s0;
    float m1 = stats[c2 + 1] * INV_N, q1 = stats[129 + c2] * INV_N;
    float inv1 = rsqrtf(q1 - m1 * m1 + BN_EPS);
    float s1 = g[c2 + 1] * inv1, t1 = b[c2 + 1] - m1 * s1;
    int s = gstart[gid], e = gstart[gid + 1];
    float a0 = 0.f, a1 = 0.f;
    int n = s + chunk * 4 + rs;
    for (; n + 16 < e; n += 32){
        unsigned u0 = z32[n * 64 + c];
        unsigned u1 = z32[(n + 16) * 64 + c];
        float f0, f1;
        f0 = fmaxf(bflo(u0) * s0 + t0, 0.f); f1 = fmaxf(bfhi(u0) * s1 + t1, 0.f);
        h32[n * 64 + c] = packbf(f0, f1); a0 += f0; a1 += f1;
        f0 = fmaxf(bflo(u1) * s0 + t0, 0.f); f1 = fmaxf(bfhi(u1) * s1 + t1, 0.f);
        h32[(n + 16) * 64 + c] = packbf(f0, f1); a0 += f0; a1 += f1;
    }
    for (; n < e; n += 16){
        unsigned u = z32[n * 64 + c];
        float f0 = fmaxf(bflo(u) * s0 + t0, 0.f);
        float f1 = fmaxf(bfhi(u) * s1 + t1, 0.f);
        h32[n * 64 + c] = packbf(f0, f1);
        a0 += f0; a1 += f1;
    }
    sd[tid] = a0; sd[256 + tid] = a1; __syncthreads();
    if (tid < 64){
        float r0 = 0.f, r1 = 0.f;
        #pragma unroll
        for (int k2 = 0; k2 < 4; k2++){ r0 += sd[tid + 64 * k2]; r1 += sd[256 + tid + 64 * k2]; }
        atomicAdd(&outp[gid * 128 + 2 * tid], r0);
        atomicAdd(&outp[gid * 128 + 2 * tid + 1], r1);
    }
}

// logits = sum_i pooled_i @ fcW_i + fcb_i ; out = log_softmax(logits)
__global__ __launch_bounds__(64) void final_k(const float* __restrict__ pooled,
                                              const float* __restrict__ fcW,
                                              const float* __restrict__ fcb,
                                              float* __restrict__ out){
    int g = blockIdx.x, l = threadIdx.x;
    float p0[5], p1[5];
    #pragma unroll
    for (int i = 0; i < 5; i++){
        p0[i] = pooled[i * GD + g * 128 + l];
        p1[i] = pooled[i * GD + g * 128 + 64 + l];
    }
    float lg[10];
    #pragma unroll
    for (int c2 = 0; c2 < 10; c2++){
        float s = 0;
        #pragma unroll
        for (int i = 0; i < 5; i++){
            s += p0[i] * fcW[(i * 128 + l) * 10 + c2];
            s += p1[i] * fcW[(i * 128 + 64 + l) * 10 + c2];
        }
        #pragma unroll
        for (int off = 32; off >= 1; off >>= 1) s += __shfl_down(s, off);
        lg[c2] = s;
    }
    if (l == 0){
        #pragma unroll
        for (int c2 = 0; c2 < 10; c2++){
            float bs = 0;
            #pragma unroll
            for (int i = 0; i < 5; i++) bs += fcb[i * 10 + c2];
            lg[c2] += bs;
        }
        float mx = lg[0];
        #pragma unroll
        for (int c2 = 1; c2 < 10; c2++) mx = fmaxf(mx, lg[c2]);
        float se = 0;
        #pragma unroll
        for (int c2 = 0; c2 < 10; c2++) se += expf(lg[c2] - mx);
        float lse = mx + logf(se);
        #pragma unroll
        for (int c2 = 0; c2 < 10; c2++) out[g * 10 + c2] = lg[c2] - lse;
    }
}

// ---------------- launch ----------------

extern "C" void kernel_launch(void* const* d_in, const int* in_sizes, int n_in,
                              void* d_out, int out_size, void* d_ws, size_t ws_size,
                              hipStream_t stream){
    (void)in_sizes; (void)n_in; (void)out_size; (void)ws_size;
    const float* x     = (const float*)d_in[0];
    const int*   ei    = (const int*)d_in[1];
    const int*   batch = (const int*)d_in[2];
    const float* cW1   = (const float*)d_in[4];
    const float* cb1   = (const float*)d_in[5];
    const float* cbng  = (const float*)d_in[6];
    const float* cbnb  = (const float*)d_in[7];
    const float* cW2   = (const float*)d_in[8];
    const float* cb2   = (const float*)d_in[9];
    const float* bng   = (const float*)d_in[10];
    const float* bnb   = (const float*)d_in[11];
    const float* fcW   = (const float*)d_in[12];
    const float* fcb   = (const float*)d_in[13];

    char* base = (char*)d_ws;
    size_t off = 0;
    auto alloc = [&](size_t bytes) -> void* {
        void* p = base + off;
        off = (off + bytes + 255) & ~(size_t)255;
        return p;
    };
    unsigned*       hB     = (unsigned*)alloc((size_t)NN * 64 * 4);
    unsigned*       zA     = (unsigned*)alloc((size_t)NN * 64 * 4);
    unsigned*       zB     = (unsigned*)alloc((size_t)NN * 64 * 4);   // also binned (NB*BUCKCAP*4 = 12.54MB)
    unsigned short* Wtall  = (unsigned short*)alloc(8 * 16384 * 2);
    int*            ssort  = (int*)alloc((size_t)EE * 4);
    int*            rp     = (int*)alloc((NN + 1) * 4);
    int*            gstart = (int*)alloc((GG + 1) * 4);
    int*            bucketBase = (int*)alloc((NB + 1) * 4);
    // ---- contiguous zero region: bucketCur .. pooled slot 0 ----
    int*            bucketCur  = (int*)alloc(NB * 4);
    float*          pooled = (float*)alloc((size_t)5 * GD * 4);
    // ------------------------------------------------------------
    float*          stats1 = (float*)alloc(256 * 4);
    float*          stats2 = (float*)alloc(256 * 4);
    unsigned*       binned = (unsigned*)zB;   // alias: binned only used before layer loop

    int zwords = (int)(((char*)(pooled + GD) - (char*)bucketCur) / 4);  // incl. pooled[0] slot

    zero_k<<<(zwords + 255) / 256, 256, 0, stream>>>(bucketCur, zwords);
    wprep_k<<<512, 256, 0, stream>>>(cW1, cW2, Wtall);
    gsearch_k<<<3, 256, 0, stream>>>(batch, gstart);
    binA_k<<<(EE + BK_EDGES - 1) / BK_EDGES, 256, 0, stream>>>(ei, ei + EE, bucketCur, binned);
    bscan_k<<<1, 256, 0, stream>>>(bucketCur, bucketBase, rp);
    binB_k<<<NB, 1024, 0, stream>>>(binned, bucketCur, bucketBase, rp, ssort);
    convxpool_k<<<4 * GG, 256, 0, stream>>>((const float2*)x, gstart, hB, pooled);

    const int gemmGrid = 2 * ((NN + 127) / 128);
    for (int i = 0; i < LLAY; i++){
        agg_k<<<NN / 4, 256, 0, stream>>>(hB, rp, ssort, zA, stats1);
        gemm_k<0><<<gemmGrid, 256, 0, stream>>>(zA, Wtall + i * 16384, cb1 + i * 128,
                                                (unsigned short*)zB,
                                                nullptr, nullptr, nullptr, stats1, stats2, nullptr);
        gemm_k<1><<<gemmGrid, 256, 0, stream>>>(zB, Wtall + (4 + i) * 16384, cb2 + i * 128,
                                                (unsigned short*)zA,
                                                stats1, cbng + i * 128, cbnb + i * 128, stats2, nullptr,
                                                pooled + (size_t)(i + 1) * GD);
        ewpool_k<<<4 * GG, 256, 0, stream>>>(zA, stats2, bng + i * 128, bnb + i * 128,
                                             gstart, hB, pooled + (size_t)(i + 1) * GD);
    }
    final_k<<<GG, 64, 0, stream>>>(pooled, fcW, fcb, (float*)d_out);
}

// Round 15
// 544.492 us; speedup vs baseline: 1.1116x; 1.0040x over previous
//
#include <hip/hip_runtime.h>

#define NN 50000
#define EE 1600000
#define DD 128
#define CC 10
#define LLAY 4
#define GG 512
#define GD (GG*DD)
#define NB 196           // ceil(NN/256) coarse buckets
#define BK_EDGES 1600    // edges per binA block (1000 blocks)
#define BUCKCAP 16000    // fixed binned region per bucket (expected 8192, >8 sigma safe)
#define NSUB 16          // src sub-tiles per node list (sorted gather window)
#define SUBW 3125        // 50000/16
#define WPAD 136         // Wl row stride in shorts (272B = 17 uint4: 2-way banks = free)

static constexpr float BN_EPS = 1e-5f;
static constexpr float INV_N = 1.0f / (float)NN;

typedef __bf16 bf16x8 __attribute__((ext_vector_type(8)));
typedef float f32x4 __attribute__((ext_vector_type(4)));

static __device__ __forceinline__ float bflo(unsigned u){ return __uint_as_float(u << 16); }
static __device__ __forceinline__ float bfhi(unsigned u){ return __uint_as_float(u & 0xffff0000u); }
static __device__ __forceinline__ unsigned short f2bf(float f){
    unsigned u = __float_as_uint(f);
    return (unsigned short)((u + 0x7fffu + ((u >> 16) & 1u)) >> 16);   // RNE
}
static __device__ __forceinline__ unsigned packbf(float a, float b){
    return (unsigned)f2bf(a) | ((unsigned)f2bf(b) << 16);
}
static __device__ __forceinline__ bf16x8 ldfrag(const unsigned short* p){
    union { uint4 u; bf16x8 b; } t; t.u = *(const uint4*)p; return t.b;
}
static __device__ __forceinline__ bf16x8 asfrag(uint4 u){
    union { uint4 u; bf16x8 b; } t; t.u = u; return t.b;
}

// ---------------- setup kernels ----------------

__global__ void zero_k(int* p, int n){
    int i = blockIdx.x * 256 + threadIdx.x;
    if (i < n) p[i] = 0;
}

// all 8 weight matrices -> bf16 W^T [j][k] in ws
__global__ void wprep_k(const float* __restrict__ W1, const float* __restrict__ W2,
                        unsigned short* __restrict__ Wtall){
    int idx = blockIdx.x * 256 + threadIdx.x;         // < 8*16384
    int mat = idx >> 14; int rr = idx & 16383;
    int k = rr >> 7; int j = rr & 127;
    const float* Wsrc = (mat < 4) ? (W1 + mat * 16384) : (W2 + (mat - 4) * 16384);
    Wtall[mat * 16384 + j * 128 + k] = f2bf(Wsrc[k * 128 + j]);
}

// graph boundaries via binary search on sorted batch
__global__ void gsearch_k(const int* __restrict__ batch, int* __restrict__ gstart){
    int g = blockIdx.x * 256 + threadIdx.x;
    if (g <= GG){
        int lo = 0, hi = NN;
        while (lo < hi){ int mid = (lo + hi) >> 1; if (batch[mid] < g) lo = mid + 1; else hi = mid; }
        gstart[g] = lo;
    }
}

// Pass A: bin edges into NB fixed-capacity bucket regions (binned[b*BUCKCAP + ...]).
// bucketCur[b] accumulates the per-bucket count (pre-zeroed).
__global__ __launch_bounds__(256) void binA_k(const int* __restrict__ srcA,
                                              const int* __restrict__ dstA,
                                              int* __restrict__ bucketCur,
                                              unsigned* __restrict__ binned){
    __shared__ int cnt[NB], bas[NB], off[NB];
    int tid = threadIdx.x;
    if (tid < NB){ cnt[tid] = 0; off[tid] = 0; }
    __syncthreads();
    int e0 = blockIdx.x * BK_EDGES;
    for (int i = tid; i < BK_EDGES; i += 256){
        int e = e0 + i;
        if (e < EE) atomicAdd(&cnt[dstA[e] >> 8], 1);
    }
    __syncthreads();
    if (tid < NB && cnt[tid] > 0) bas[tid] = atomicAdd(&bucketCur[tid], cnt[tid]);
    __syncthreads();
    for (int i = tid; i < BK_EDGES; i += 256){
        int e = e0 + i;
        if (e < EE){
            int d = dstA[e]; int b = d >> 8;
            int p = b * BUCKCAP + bas[b] + atomicAdd(&off[b], 1);
            binned[p] = (unsigned)srcA[e] | ((unsigned)(d & 255) << 17);  // src<2^17
        }
    }
}

// scan bucket counts (post-binA) -> bucketBase; terminal rp entry
__global__ __launch_bounds__(256) void bscan_k(const int* __restrict__ bucketCur,
                                               int* __restrict__ bucketBase,
                                               int* __restrict__ rp){
    __shared__ int lds[256];
    int t = threadIdx.x;
    int v = (t < NB) ? bucketCur[t] : 0;
    lds[t] = v; __syncthreads();
    for (int o = 1; o < 256; o <<= 1){
        int xv = 0; if (t >= o) xv = lds[t - o];
        __syncthreads(); lds[t] += xv; __syncthreads();
    }
    int excl = lds[t] - v;
    if (t < NB) bucketBase[t] = excl;
    if (t == 0){ bucketBase[NB] = EE; rp[NN] = EE; }
}

// Pass B (1024 thr): per-bucket (node, 16-subtile) counts -> rp + src-sorted placement.
__global__ __launch_bounds__(1024) void binB_k(const unsigned* __restrict__ binned,
                                               const int* __restrict__ bucketCur,
                                               const int* __restrict__ bucketBase,
                                               int* __restrict__ rp,
                                               int* __restrict__ ssort){
    __shared__ int c16[256 * NSUB];   // 16 KB
    __shared__ int b16[256 * NSUB];   // 16 KB
    __shared__ int nt[256];
    int b = blockIdx.x, tid = threadIdx.x;
    int nb0 = b * 256;
    int nmax = NN - nb0; if (nmax > 256) nmax = 256;
    for (int i = tid; i < 256 * NSUB; i += 1024) c16[i] = 0;
    __syncthreads();
    int cntb = bucketCur[b];
    int src0 = b * BUCKCAP;
    int base = bucketBase[b];
    for (int i = tid; i < cntb; i += 1024){
        unsigned u = binned[src0 + i];
        int src = (int)(u & 0x1FFFFu); int dl = (int)(u >> 17);
        atomicAdd(&c16[dl * NSUB + src / SUBW], 1);
    }
    __syncthreads();
    int cc[NSUB]; int tot = 0;
    if (tid < 256){
        #pragma unroll
        for (int k = 0; k < NSUB; k++){ cc[k] = c16[tid * NSUB + k]; tot += cc[k]; }
        nt[tid] = tot;
    }
    __syncthreads();
    for (int o = 1; o < 256; o <<= 1){
        int xv = 0;
        if (tid < 256 && tid >= o) xv = nt[tid - o];
        __syncthreads();
        if (tid < 256) nt[tid] += xv;
        __syncthreads();
    }
    if (tid < 256){
        int p = base + nt[tid] - tot;
        if (tid < nmax) rp[nb0 + tid] = p;
        int run = p;
        #pragma unroll
        for (int k = 0; k < NSUB; k++){ b16[tid * NSUB + k] = run; run += cc[k]; }
    }
    __syncthreads();
    for (int i = tid; i < 256 * NSUB; i += 1024) c16[i] = 0;
    __syncthreads();
    for (int i = tid; i < cntb; i += 1024){
        unsigned u = binned[src0 + i];
        int src = (int)(u & 0x1FFFFu); int dl = (int)(u >> 17);
        int t = src / SUBW;
        int pos = b16[dl * NSUB + t] + atomicAdd(&c16[dl * NSUB + t], 1);
        ssort[pos] = src;
    }
}

// x (fp32) -> bf16 h, fused with graph pooling of x. 4 blocks per graph.
__global__ __launch_bounds__(256) void convxpool_k(const float2* __restrict__ x2,
                                                   const int* __restrict__ gstart,
                                                   unsigned* __restrict__ h32,
                                                   float* __restrict__ outp){
    __shared__ float sd[512];
    int b = blockIdx.x; int gid = b >> 2, chunk = b & 3;
    int tid = threadIdx.x; int c = tid & 63, rs = tid >> 6;
    int s = gstart[gid], e = gstart[gid + 1];
    float a0 = 0.f, a1 = 0.f;
    for (int n = s + chunk * 4 + rs; n < e; n += 16){
        float2 v = x2[n * 64 + c];
        h32[n * 64 + c] = packbf(v.x, v.y);
        a0 += v.x; a1 += v.y;
    }
    sd[tid] = a0; sd[256 + tid] = a1; __syncthreads();
    if (tid < 64){
        float r0 = 0.f, r1 = 0.f;
        #pragma unroll
        for (int k2 = 0; k2 < 4; k2++){ r0 += sd[tid + 64 * k2]; r1 += sd[256 + tid + 64 * k2]; }
        atomicAdd(&outp[gid * 128 + 2 * tid], r0);
        atomicAdd(&outp[gid * 128 + 2 * tid + 1], r1);
    }
}

// ---------------- per-layer kernels ----------------

// z = h + sum_{in-edges} h[src]  (dword gathers, unroll 16)
__global__ __launch_bounds__(256) void agg_k(const unsigned* __restrict__ h32,
                                             const int* __restrict__ rp,
                                             const int* __restrict__ ssort,
                                             unsigned* __restrict__ z32,
                                             float* __restrict__ zstats){
    int tid = threadIdx.x;
    if (blockIdx.x == 0) zstats[tid] = 0.f;
    int n = blockIdx.x * 4 + (tid >> 6);  // grid*4 == NN exactly
    int lane = tid & 63;
    unsigned self = h32[n * 64 + lane];
    float ax = bflo(self), ay = bfhi(self);
    int e  = __builtin_amdgcn_readfirstlane(rp[n]);
    int e1 = __builtin_amdgcn_readfirstlane(rp[n + 1]);
    for (; e + 15 < e1; e += 16){
        int sA[16];
        #pragma unroll
        for (int k = 0; k < 16; k++) sA[k] = ssort[e + k];
        unsigned uA[16];
        #pragma unroll
        for (int k = 0; k < 16; k++) uA[k] = h32[sA[k] * 64 + lane];
        #pragma unroll
        for (int k = 0; k < 16; k++){ ax += bflo(uA[k]); ay += bfhi(uA[k]); }
    }
    for (; e + 3 < e1; e += 4){
        int s0 = ssort[e], s1 = ssort[e + 1], s2 = ssort[e + 2], s3 = ssort[e + 3];
        unsigned u0 = h32[s0 * 64 + lane];
        unsigned u1 = h32[s1 * 64 + lane];
        unsigned u2 = h32[s2 * 64 + lane];
        unsigned u3 = h32[s3 * 64 + lane];
        ax += bflo(u0) + bflo(u1); ay += bfhi(u0) + bfhi(u1);
        ax += bflo(u2) + bflo(u3); ay += bfhi(u2) + bfhi(u3);
    }
    for (; e < e1; ++e){
        unsigned u0 = h32[ssort[e] * 64 + lane];
        ax += bflo(u0); ay += bfhi(u0);
    }
    z32[n * 64 + lane] = packbf(ax, ay);
}

// C[N, 64-col slice] = opt_relu_bn(A[N,128]) @ W-slice + bias, bf16 MFMA 16x16x32.
// 128-row x 64-col tile, blockIdx = tile*2 + slice, 782 blocks.
// A-loads issued BEFORE the W-stage barrier (latency overlap); Wl padded -> no conflicts.
// Fused epilogue: column sum/sumsq -> atomicAdd into ostats. Blocks 0..255 zero zpool if given.
template<int TR>
__global__ __launch_bounds__(256) void gemm_k(const unsigned* __restrict__ A32,
                                              const unsigned short* __restrict__ Wtg,
                                              const float* __restrict__ bias,
                                              unsigned short* __restrict__ Cst,
                                              const float* __restrict__ stats,
                                              const float* __restrict__ gma,
                                              const float* __restrict__ bta,
                                              float* __restrict__ ostats,
                                              float* __restrict__ zstats,
                                              float* __restrict__ zpool){
    __shared__ __align__(16) unsigned short Wl[64 * WPAD];  // 17.4KB, [j][k] padded
    __shared__ float sred[512];
    __shared__ __align__(16) float sl[128], tl[128];
    int tid = threadIdx.x;
    int slice = blockIdx.x & 1;
    int tileb = blockIdx.x >> 1;

    // ---- issue A-loads first: their ~L3 latency overlaps W-staging + barrier ----
    int wv = tid >> 6, lane = tid & 63;
    int rowbase = tileb * 128 + wv * 32;
    int r0 = rowbase + (lane & 15);
    int r1 = r0 + 16;
    int kd = (lane >> 4) * 4;       // dword offset within 16-dword k-group
    uint4 va[4], vb[4];
    #pragma unroll
    for (int ks = 0; ks < 4; ks++){
        va[ks] = (r0 < NN) ? *(const uint4*)(A32 + r0 * 64 + ks * 16 + kd) : make_uint4(0,0,0,0);
        vb[ks] = (r1 < NN) ? *(const uint4*)(A32 + r1 * 64 + ks * 16 + kd) : make_uint4(0,0,0,0);
    }

    if (blockIdx.x == 0 && zstats) zstats[tid] = 0.f;
    if (zpool && blockIdx.x < 256) zpool[blockIdx.x * 256 + tid] = 0.f;
    {   // stage 64 W^T rows [slice*64, slice*64+64): each row = 16 uint4, padded to 17
        const uint4* src = (const uint4*)(Wtg + slice * 64 * 128);
        uint4* dst = (uint4*)Wl;
        #pragma unroll
        for (int i = 0; i < 4; i++){
            int idx = tid + 256 * i;            // 0..1023
            int row = idx >> 4, c16 = idx & 15; // 64 rows x 16 uint4
            dst[row * (WPAD / 8) + c16] = src[idx];
        }
    }
    if (TR && tid < 128){
        float mean = stats[tid] * INV_N;
        float q    = stats[128 + tid] * INV_N;
        float inv  = rsqrtf(q - mean * mean + BN_EPS);
        float s    = gma[tid] * inv;
        sl[tid] = s; tl[tid] = bta[tid] - mean * s;
    }
    __syncthreads();

    if (TR){
        #pragma unroll
        for (int ks = 0; ks < 4; ks++){
            int q = ks * 8 + (lane >> 4) * 2;       // float4 index: k0/4
            float4 sA = ((const float4*)sl)[q], sB = ((const float4*)sl)[q + 1];
            float4 tA = ((const float4*)tl)[q], tB = ((const float4*)tl)[q + 1];
            float fs[8] = {sA.x, sA.y, sA.z, sA.w, sB.x, sB.y, sB.z, sB.w};
            float ft[8] = {tA.x, tA.y, tA.z, tA.w, tB.x, tB.y, tB.z, tB.w};
            unsigned* pa = (unsigned*)&va[ks];
            unsigned* pb = (unsigned*)&vb[ks];
            #pragma unroll
            for (int c = 0; c < 4; c++){
                float f0 = fmaxf(bflo(pa[c]) * fs[2*c] + ft[2*c], 0.f);
                float f1 = fmaxf(bfhi(pa[c]) * fs[2*c+1] + ft[2*c+1], 0.f);
                pa[c] = packbf(f0, f1);
                f0 = fmaxf(bflo(pb[c]) * fs[2*c] + ft[2*c], 0.f);
                f1 = fmaxf(bfhi(pb[c]) * fs[2*c+1] + ft[2*c+1], 0.f);
                pb[c] = packbf(f0, f1);
            }
        }
    }

    f32x4 acc[2][4];
    #pragma unroll
    for (int a = 0; a < 2; a++)
        #pragma unroll
        for (int b = 0; b < 4; b++) acc[a][b] = (f32x4){0.f, 0.f, 0.f, 0.f};

    #pragma unroll
    for (int ks = 0; ks < 4; ks++){
        int wk = ks * 32 + (lane >> 4) * 8;
        bf16x8 a0 = asfrag(va[ks]);
        bf16x8 a1 = asfrag(vb[ks]);
        #pragma unroll
        for (int ct = 0; ct < 4; ++ct){
            bf16x8 b = ldfrag(&Wl[(ct * 16 + (lane & 15)) * WPAD + wk]);
            acc[0][ct] = __builtin_amdgcn_mfma_f32_16x16x32_bf16(a0, b, acc[0][ct], 0, 0, 0);
            acc[1][ct] = __builtin_amdgcn_mfma_f32_16x16x32_bf16(a1, b, acc[1][ct], 0, 0, 0);
        }
    }

    // epilogue: C/D layout col=lane&15, row=(lane>>4)*4+reg. Store + column stats.
    int cl = lane & 15, rq = lane >> 4;
    float colS[4], colQ[4];
    #pragma unroll
    for (int ct = 0; ct < 4; ++ct){
        int col = slice * 64 + ct * 16 + cl;
        float bv = bias[col];
        float ps = 0.f, pq = 0.f;
        #pragma unroll
        for (int rt = 0; rt < 2; ++rt){
            #pragma unroll
            for (int rr2 = 0; rr2 < 4; ++rr2){
                int grow = rowbase + rt * 16 + rq * 4 + rr2;
                if (grow < NN){
                    float val = acc[rt][ct][rr2] + bv;
                    Cst[grow * 128 + col] = f2bf(val);
                    ps += val; pq += val * val;
                }
            }
        }
        ps += __shfl_xor(ps, 16); pq += __shfl_xor(pq, 16);
        ps += __shfl_xor(ps, 32); pq += __shfl_xor(pq, 32);
        colS[ct] = ps; colQ[ct] = pq;
    }
    if (rq == 0){
        #pragma unroll
        for (int ct = 0; ct < 4; ++ct){
            sred[wv * 64 + ct * 16 + cl]       = colS[ct];
            sred[256 + wv * 64 + ct * 16 + cl] = colQ[ct];
        }
    }
    __syncthreads();
    if (tid < 64){
        float s1 = sred[tid] + sred[64 + tid] + sred[128 + tid] + sred[192 + tid];
        float s2 = sred[256 + tid] + sred[320 + tid] + sred[384 + tid] + sred[448 + tid];
        atomicAdd(&ostats[slice * 64 + tid], s1);
        atomicAdd(&ostats[128 + slice * 64 + tid], s2);
    }
}

// h = relu(bn(z)) (write h) fused with per-graph pooling. 4 blocks per graph.
__global__ __launch_bounds__(256) void ewpool_k(const unsigned* __restrict__ z32,
                                                const float* __restrict__ stats,
                                                const float* __restrict__ g,
                                                const float* __restrict__ b,
                                                const int* __restrict__ gstart,
                                                unsigned* __restrict__ h32,
                                                float* __restrict__ outp){
    __shared__ float sd[512];
    int blk = blockIdx.x; int gid = blk >> 2, chunk = blk & 3;
    int tid = threadIdx.x;
    int c = tid & 63, rs = tid >> 6;
    int c2 = c * 2;
    float m0 = stats[c2] * INV_N,     q0 = stats[128 + c2] * INV_N;
    float inv0 = rsqrtf(q0 - m0 * m0 + BN_EPS);
    float s0 = g[c2] * inv0, t0 = b[c2] - m0 * s0;
    float m1 = stats[c2 + 1] * INV_N, q1 = stats[129 + c2] * INV_N;
    float inv1 = rsqrtf(q1 - m1 * m1 + BN_EPS);
    float s1 = g[c2 + 1] * inv1, t1 = b[c2 + 1] - m1 * s1;
    int s = gstart[gid], e = gstart[gid + 1];
    float a0 = 0.f, a1 = 0.f;
    int n = s + chunk * 4 + rs;
    for (; n + 16 < e; n += 32){
        unsigned u0 = z32[n * 64 + c];
        unsigned u1 = z32[(n + 16) * 64 + c];
        float f0, f1;
        f0 = fmaxf(bflo(u0) * s0 + t0, 0.f); f1 = fmaxf(bfhi(u0) * s1 + t1, 0.f);
        h32[n * 64 + c] = packbf(f0, f1); a0 += f0; a1 += f1;
        f0 = fmaxf(bflo(u1) * s0 + t0, 0.f); f1 = fmaxf(bfhi(u1) * s1 + t1, 0.f);
        h32[(n + 16) * 64 + c] = packbf(f0, f1); a0 += f0; a1 += f1;
    }
    for (; n < e; n += 16){
        unsigned u = z32[n * 64 + c];
        float f0 = fmaxf(bflo(u) * s0 + t0, 0.f);
        float f1 = fmaxf(bfhi(u) * s1 + t1, 0.f);
        h32[n * 64 + c] = packbf(f0, f1);
        a0 += f0; a1 += f1;
    }
    sd[tid] = a0; sd[256 + tid] = a1; __syncthreads();
    if (tid < 64){
        float r0 = 0.f, r1 = 0.f;
        #pragma unroll
        for (int k2 = 0; k2 < 4; k2++){ r0 += sd[tid + 64 * k2]; r1 += sd[256 + tid + 64 * k2]; }
        atomicAdd(&outp[gid * 128 + 2 * tid], r0);
        atomicAdd(&outp[gid * 128 + 2 * tid + 1], r1);
    }
}

// logits = sum_i pooled_i @ fcW_i + fcb_i ; out = log_softmax(logits)
__global__ __launch_bounds__(64) void final_k(const float* __restrict__ pooled,
                                              const float* __restrict__ fcW,
                                              const float* __restrict__ fcb,
                                              float* __restrict__ out){
    int g = blockIdx.x, l = threadIdx.x;
    float p0[5], p1[5];
    #pragma unroll
    for (int i = 0; i < 5; i++){
        p0[i] = pooled[i * GD + g * 128 + l];
        p1[i] = pooled[i * GD + g * 128 + 64 + l];
    }
    float lg[10];
    #pragma unroll
    for (int c2 = 0; c2 < 10; c2++){
        float s = 0;
        #pragma unroll
        for (int i = 0; i < 5; i++){
            s += p0[i] * fcW[(i * 128 + l) * 10 + c2];
            s += p1[i] * fcW[(i * 128 + 64 + l) * 10 + c2];
        }
        #pragma unroll
        for (int off = 32; off >= 1; off >>= 1) s += __shfl_down(s, off);
        lg[c2] = s;
    }
    if (l == 0){
        #pragma unroll
        for (int c2 = 0; c2 < 10; c2++){
            float bs = 0;
            #pragma unroll
            for (int i = 0; i < 5; i++) bs += fcb[i * 10 + c2];
            lg[c2] += bs;
        }
        float mx = lg[0];
        #pragma unroll
        for (int c2 = 1; c2 < 10; c2++) mx = fmaxf(mx, lg[c2]);
        float se = 0;
        #pragma unroll
        for (int c2 = 0; c2 < 10; c2++) se += expf(lg[c2] - mx);
        float lse = mx + logf(se);
        #pragma unroll
        for (int c2 = 0; c2 < 10; c2++) out[g * 10 + c2] = lg[c2] - lse;
    }
}

// ---------------- launch ----------------

extern "C" void kernel_launch(void* const* d_in, const int* in_sizes, int n_in,
                              void* d_out, int out_size, void* d_ws, size_t ws_size,
                              hipStream_t stream){
    (void)in_sizes; (void)n_in; (void)out_size; (void)ws_size;
    const float* x     = (const float*)d_in[0];
    const int*   ei    = (const int*)d_in[1];
    const int*   batch = (const int*)d_in[2];
    const float* cW1   = (const float*)d_in[4];
    const float* cb1   = (const float*)d_in[5];
    const float* cbng  = (const float*)d_in[6];
    const float* cbnb  = (const float*)d_in[7];
    const float* cW2   = (const float*)d_in[8];
    const float* cb2   = (const float*)d_in[9];
    const float* bng   = (const float*)d_in[10];
    const float* bnb   = (const float*)d_in[11];
    const float* fcW   = (const float*)d_in[12];
    const float* fcb   = (const float*)d_in[13];

    char* base = (char*)d_ws;
    size_t off = 0;
    auto alloc = [&](size_t bytes) -> void* {
        void* p = base + off;
        off = (off + bytes + 255) & ~(size_t)255;
        return p;
    };
    unsigned*       hB     = (unsigned*)alloc((size_t)NN * 64 * 4);
    unsigned*       zA     = (unsigned*)alloc((size_t)NN * 64 * 4);
    unsigned*       zB     = (unsigned*)alloc((size_t)NN * 64 * 4);   // also binned (NB*BUCKCAP*4 = 12.54MB)
    unsigned short* Wtall  = (unsigned short*)alloc(8 * 16384 * 2);
    int*            ssort  = (int*)alloc((size_t)EE * 4);
    int*            rp     = (int*)alloc((NN + 1) * 4);
    int*            gstart = (int*)alloc((GG + 1) * 4);
    int*            bucketBase = (int*)alloc((NB + 1) * 4);
    // ---- contiguous zero region: bucketCur .. pooled slot 0 ----
    int*            bucketCur  = (int*)alloc(NB * 4);
    float*          pooled = (float*)alloc((size_t)5 * GD * 4);
    // ------------------------------------------------------------
    float*          stats1 = (float*)alloc(256 * 4);
    float*          stats2 = (float*)alloc(256 * 4);
    unsigned*       binned = (unsigned*)zB;   // alias: binned only used before layer loop

    int zwords = (int)(((char*)(pooled + GD) - (char*)bucketCur) / 4);  // incl. pooled[0] slot

    zero_k<<<(zwords + 255) / 256, 256, 0, stream>>>(bucketCur, zwords);
    wprep_k<<<512, 256, 0, stream>>>(cW1, cW2, Wtall);
    gsearch_k<<<3, 256, 0, stream>>>(batch, gstart);
    binA_k<<<(EE + BK_EDGES - 1) / BK_EDGES, 256, 0, stream>>>(ei, ei + EE, bucketCur, binned);
    bscan_k<<<1, 256, 0, stream>>>(bucketCur, bucketBase, rp);
    binB_k<<<NB, 1024, 0, stream>>>(binned, bucketCur, bucketBase, rp, ssort);
    convxpool_k<<<4 * GG, 256, 0, stream>>>((const float2*)x, gstart, hB, pooled);

    const int gemmGrid = 2 * ((NN + 127) / 128);
    for (int i = 0; i < LLAY; i++){
        agg_k<<<NN / 4, 256, 0, stream>>>(hB, rp, ssort, zA, stats1);
        gemm_k<0><<<gemmGrid, 256, 0, stream>>>(zA, Wtall + i * 16384, cb1 + i * 128,
                                                (unsigned short*)zB,
                                                nullptr, nullptr, nullptr, stats1, stats2, nullptr);
        gemm_k<1><<<gemmGrid, 256, 0, stream>>>(zB, Wtall + (4 + i) * 16384, cb2 + i * 128,
                                                (unsigned short*)zA,
                                                stats1, cbng + i * 128, cbnb + i * 128, stats2, nullptr,
                                                pooled + (size_t)(i + 1) * GD);
        ewpool_k<<<4 * GG, 256, 0, stream>>>(zA, stats2, bng + i * 128, bnb + i * 128,
                                             gstart, hB, pooled + (size_t)(i + 1) * GD);
    }
    final_k<<<GG, 64, 0, stream>>>(pooled, fcW, fcb, (float*)d_out);
}